// Round 2
// baseline (197.208 us; speedup 1.0000x reference)
//
#include <hip/hip_runtime.h>
#include <hip/hip_bf16.h>

// Problem constants
#define BATCH 8
#define HH 56
#define WW 56
#define NPOS (BATCH*HH*WW)   // 25088
#define C 256
#define P 32
#define D 4
#define J (P*D)              // 128
#define EPS 1e-3f

// ---------------------------------------------------------------------------
// Fold BN into conv weights/biases: bn(h) = s*h + t, s = g*rsqrt(v+eps),
// t = be - m*s.  conv+bias then bn  ==  conv with W*s, bias B*s + t.
// ---------------------------------------------------------------------------
__global__ __launch_bounds__(256) void fold_params(
    const float* __restrict__ W1, const float* __restrict__ B1,
    const float* __restrict__ W2, const float* __restrict__ B2,
    const float* __restrict__ W3, const float* __restrict__ B3,
    const float* __restrict__ G1, const float* __restrict__ Be1,
    const float* __restrict__ M1, const float* __restrict__ V1,
    const float* __restrict__ G2, const float* __restrict__ Be2,
    const float* __restrict__ M2, const float* __restrict__ V2,
    const float* __restrict__ G3, const float* __restrict__ Be3,
    const float* __restrict__ M3, const float* __restrict__ V3,
    float* __restrict__ W1f, float* __restrict__ b1f,
    float* __restrict__ W2f, float* __restrict__ b2f,
    float* __restrict__ W3f, float* __restrict__ b3f)
{
    int idx = blockIdx.x * 256 + threadIdx.x;

    // W1f[c*128 + j], j = p*4+d  (stage-1 GEMM B-matrix, K-major)
    if (idx < C*J) {
        int c = idx >> 7, j = idx & 127;
        int p = j >> 2, d = j & 3;
        float s = G1[j] * rsqrtf(V1[j] + EPS);
        W1f[idx] = W1[(p*C + c)*D + d] * s;
        return;
    }
    idx -= C*J;
    if (idx < J) {
        float s = G1[idx] * rsqrtf(V1[idx] + EPS);
        b1f[idx] = B1[idx] * s + Be1[idx] - M1[idx] * s;
        return;
    }
    idx -= J;
    // W2f flat (P,3,3,Din,Dout) -- same layout as input, scaled on 'dout' (innermost)
    if (idx < P*9*D*D) {
        int p = idx / (9*D*D);
        int dd = idx & 3;               // output channel within path
        int j = p*4 + dd;
        float s = G2[j] * rsqrtf(V2[j] + EPS);
        W2f[idx] = W2[idx] * s;
        return;
    }
    idx -= P*9*D*D;
    if (idx < J) {
        float s = G2[idx] * rsqrtf(V2[idx] + EPS);
        b2f[idx] = B2[idx] * s + Be2[idx] - M2[idx] * s;
        return;
    }
    idx -= J;
    // W3f flat (P,D,C), scaled per (p,c)
    if (idx < P*D*C) {
        int c = idx & 255;
        int p = idx >> 10;              // D*C = 1024 per p
        float s = G3[p*C + c] * rsqrtf(V3[p*C + c] + EPS);
        W3f[idx] = W3[idx] * s;
        return;
    }
    idx -= P*D*C;
    if (idx < P*C) {
        float s = G3[idx] * rsqrtf(V3[idx] + EPS);
        b3f[idx] = B3[idx] * s + Be3[idx] - M3[idx] * s;
        return;
    }
}

// ---------------------------------------------------------------------------
// Stage 1: h1[n,j] = relu( sum_c x[n,c]*W1f[c,j] + b1f[j] )
// Tiled GEMM: block = 64 positions x 128 outputs, K chunks of 32.
// 256 threads, each computes 4n x 8j.
// ---------------------------------------------------------------------------
__global__ __launch_bounds__(256) void stage1(
    const float* __restrict__ x,
    const float* __restrict__ W1f, const float* __restrict__ b1f,
    float* __restrict__ h1)
{
    __shared__ float xs[64][36];     // [n][k], padded to soften bank aliasing
    __shared__ float wsh[32][128];   // [k][j]

    const int tid = threadIdx.x;
    const int n0blk = blockIdx.x * 64;
    const int jt = tid & 15;         // j0 = jt*8
    const int nt = tid >> 4;         // n0 = nt*4

    float acc[4][8];
#pragma unroll
    for (int i = 0; i < 4; ++i)
#pragma unroll
        for (int j = 0; j < 8; ++j) acc[i][j] = 0.f;

    const int nl = tid >> 2;            // 0..63
    const int kl = (tid & 3) * 8;       // 0,8,16,24

    for (int kc = 0; kc < C; kc += 32) {
        // load x tile: each thread 8 contiguous k for one row (2x float4)
        {
            const float* xp = x + (size_t)(n0blk + nl) * C + kc + kl;
            float4 a = *(const float4*)xp;
            float4 b = *(const float4*)(xp + 4);
            xs[nl][kl+0] = a.x; xs[nl][kl+1] = a.y;
            xs[nl][kl+2] = a.z; xs[nl][kl+3] = a.w;
            xs[nl][kl+4] = b.x; xs[nl][kl+5] = b.y;
            xs[nl][kl+6] = b.z; xs[nl][kl+7] = b.w;
        }
        // load W chunk: 32 x 128 floats
#pragma unroll
        for (int it = 0; it < 4; ++it) {
            int row = (tid >> 5) + it * 8;
            int col = (tid & 31) * 4;
            *(float4*)&wsh[row][col] = *(const float4*)&W1f[(size_t)(kc + row) * J + col];
        }
        __syncthreads();

#pragma unroll 8
        for (int k = 0; k < 32; ++k) {
            float xv0 = xs[nt*4+0][k];
            float xv1 = xs[nt*4+1][k];
            float xv2 = xs[nt*4+2][k];
            float xv3 = xs[nt*4+3][k];
            float4 wa = *(float4*)&wsh[k][jt*8];
            float4 wb = *(float4*)&wsh[k][jt*8+4];
            acc[0][0] = fmaf(xv0, wa.x, acc[0][0]); acc[0][1] = fmaf(xv0, wa.y, acc[0][1]);
            acc[0][2] = fmaf(xv0, wa.z, acc[0][2]); acc[0][3] = fmaf(xv0, wa.w, acc[0][3]);
            acc[0][4] = fmaf(xv0, wb.x, acc[0][4]); acc[0][5] = fmaf(xv0, wb.y, acc[0][5]);
            acc[0][6] = fmaf(xv0, wb.z, acc[0][6]); acc[0][7] = fmaf(xv0, wb.w, acc[0][7]);
            acc[1][0] = fmaf(xv1, wa.x, acc[1][0]); acc[1][1] = fmaf(xv1, wa.y, acc[1][1]);
            acc[1][2] = fmaf(xv1, wa.z, acc[1][2]); acc[1][3] = fmaf(xv1, wa.w, acc[1][3]);
            acc[1][4] = fmaf(xv1, wb.x, acc[1][4]); acc[1][5] = fmaf(xv1, wb.y, acc[1][5]);
            acc[1][6] = fmaf(xv1, wb.z, acc[1][6]); acc[1][7] = fmaf(xv1, wb.w, acc[1][7]);
            acc[2][0] = fmaf(xv2, wa.x, acc[2][0]); acc[2][1] = fmaf(xv2, wa.y, acc[2][1]);
            acc[2][2] = fmaf(xv2, wa.z, acc[2][2]); acc[2][3] = fmaf(xv2, wa.w, acc[2][3]);
            acc[2][4] = fmaf(xv2, wb.x, acc[2][4]); acc[2][5] = fmaf(xv2, wb.y, acc[2][5]);
            acc[2][6] = fmaf(xv2, wb.z, acc[2][6]); acc[2][7] = fmaf(xv2, wb.w, acc[2][7]);
            acc[3][0] = fmaf(xv3, wa.x, acc[3][0]); acc[3][1] = fmaf(xv3, wa.y, acc[3][1]);
            acc[3][2] = fmaf(xv3, wa.z, acc[3][2]); acc[3][3] = fmaf(xv3, wa.w, acc[3][3]);
            acc[3][4] = fmaf(xv3, wb.x, acc[3][4]); acc[3][5] = fmaf(xv3, wb.y, acc[3][5]);
            acc[3][6] = fmaf(xv3, wb.z, acc[3][6]); acc[3][7] = fmaf(xv3, wb.w, acc[3][7]);
        }
        __syncthreads();
    }

    float4 ba = *(const float4*)&b1f[jt*8];
    float4 bb = *(const float4*)&b1f[jt*8+4];
#pragma unroll
    for (int i = 0; i < 4; ++i) {
        int n = n0blk + nt*4 + i;
        float4 o0, o1;
        o0.x = fmaxf(acc[i][0] + ba.x, 0.f); o0.y = fmaxf(acc[i][1] + ba.y, 0.f);
        o0.z = fmaxf(acc[i][2] + ba.z, 0.f); o0.w = fmaxf(acc[i][3] + ba.w, 0.f);
        o1.x = fmaxf(acc[i][4] + bb.x, 0.f); o1.y = fmaxf(acc[i][5] + bb.y, 0.f);
        o1.z = fmaxf(acc[i][6] + bb.z, 0.f); o1.w = fmaxf(acc[i][7] + bb.w, 0.f);
        *(float4*)&h1[(size_t)n * J + jt*8]     = o0;
        *(float4*)&h1[(size_t)n * J + jt*8 + 4] = o1;
    }
}

// ---------------------------------------------------------------------------
// Stage 2: grouped 3x3 conv, 32 groups of 4->4, SAME padding, + bias, ReLU.
// One thread per (n, p): computes all 4 'dout' outputs.
// ---------------------------------------------------------------------------
__global__ __launch_bounds__(256) void stage2(
    const float* __restrict__ h1,
    const float* __restrict__ W2f, const float* __restrict__ b2f,
    float* __restrict__ h2)
{
    __shared__ float w2s[P*9*D*D];   // 4608 floats
    __shared__ float b2s[J];

    const int tid = threadIdx.x;
    for (int i = tid; i < P*9*D*D; i += 256) w2s[i] = W2f[i];
    if (tid < J) b2s[tid] = b2f[tid];
    __syncthreads();

    const int t = blockIdx.x * 256 + tid;
    const int p = t & 31;
    const int n = t >> 5;
    const int w = n % WW;
    const int h = (n / WW) % HH;
    const int b = n / (HH*WW);

    float a0 = b2s[p*4+0], a1 = b2s[p*4+1], a2 = b2s[p*4+2], a3 = b2s[p*4+3];

#pragma unroll
    for (int ky = 0; ky < 3; ++ky) {
        int yy = h + ky - 1;
        if (yy < 0 || yy >= HH) continue;
#pragma unroll
        for (int kx = 0; kx < 3; ++kx) {
            int xx = w + kx - 1;
            if (xx < 0 || xx >= WW) continue;
            float4 hv = *(const float4*)&h1[(size_t)((b*HH + yy)*WW + xx) * J + p*4];
            const float* wp = &w2s[(p*9 + ky*3 + kx) * 16];
            a0 = fmaf(hv.x, wp[0],  a0); a1 = fmaf(hv.x, wp[1],  a1);
            a2 = fmaf(hv.x, wp[2],  a2); a3 = fmaf(hv.x, wp[3],  a3);
            a0 = fmaf(hv.y, wp[4],  a0); a1 = fmaf(hv.y, wp[5],  a1);
            a2 = fmaf(hv.y, wp[6],  a2); a3 = fmaf(hv.y, wp[7],  a3);
            a0 = fmaf(hv.z, wp[8],  a0); a1 = fmaf(hv.z, wp[9],  a1);
            a2 = fmaf(hv.z, wp[10], a2); a3 = fmaf(hv.z, wp[11], a3);
            a0 = fmaf(hv.w, wp[12], a0); a1 = fmaf(hv.w, wp[13], a1);
            a2 = fmaf(hv.w, wp[14], a2); a3 = fmaf(hv.w, wp[15], a3);
        }
    }
    float4 o;
    o.x = fmaxf(a0, 0.f); o.y = fmaxf(a1, 0.f);
    o.z = fmaxf(a2, 0.f); o.w = fmaxf(a3, 0.f);
    *(float4*)&h2[(size_t)n * J + p*4] = o;
}

// ---------------------------------------------------------------------------
// Stage 3: out[n,c] = relu( x[n,c] + sum_p relu( b3f[p,c] + sum_d h2[n,p*4+d]*W3f[p,d,c] ) )
// Block: 32 positions x 256 channels; thread = one channel, 32 accumulators.
// ---------------------------------------------------------------------------
__global__ __launch_bounds__(256) void stage3(
    const float* __restrict__ h2,
    const float* __restrict__ W3f, const float* __restrict__ b3f,
    const float* __restrict__ x,
    float* __restrict__ out)
{
    __shared__ float h2s[32][J];     // 16 KB

    const int tid = threadIdx.x;
    const int n0 = blockIdx.x * 32;

#pragma unroll
    for (int r = 0; r < 4; ++r) {
        int idx = r*256 + tid;            // float4 index, 1024 total
        int n = idx >> 5;
        int q = idx & 31;
        *(float4*)&h2s[n][q*4] = *(const float4*)&h2[(size_t)(n0 + n) * J + q*4];
    }
    __syncthreads();

    const int c = tid;
    float acc[32];
#pragma unroll
    for (int i = 0; i < 32; ++i) acc[i] = 0.f;

    for (int p = 0; p < P; ++p) {
        float w0 = W3f[(size_t)(p*4+0)*C + c];
        float w1 = W3f[(size_t)(p*4+1)*C + c];
        float w2 = W3f[(size_t)(p*4+2)*C + c];
        float w3 = W3f[(size_t)(p*4+3)*C + c];
        float bb = b3f[p*C + c];
#pragma unroll
        for (int i = 0; i < 32; ++i) {
            float4 h = *(float4*)&h2s[i][p*4];   // wave-uniform -> broadcast
            float v = fmaf(h.x, w0, fmaf(h.y, w1, fmaf(h.z, w2, fmaf(h.w, w3, bb))));
            acc[i] += fmaxf(v, 0.f);
        }
    }

#pragma unroll
    for (int i = 0; i < 32; ++i) {
        float xv = x[(size_t)(n0 + i) * C + c];
        out[(size_t)(n0 + i) * C + c] = fmaxf(acc[i] + xv, 0.f);
    }
}

// ---------------------------------------------------------------------------
extern "C" void kernel_launch(void* const* d_in, const int* in_sizes, int n_in,
                              void* d_out, int out_size, void* d_ws, size_t ws_size,
                              hipStream_t stream) {
    const float* x  = (const float*)d_in[0];
    const float* W1 = (const float*)d_in[1];
    const float* B1 = (const float*)d_in[2];
    const float* W2 = (const float*)d_in[3];
    const float* B2 = (const float*)d_in[4];
    const float* W3 = (const float*)d_in[5];
    const float* B3 = (const float*)d_in[6];
    const float* G1 = (const float*)d_in[7];
    const float* Be1= (const float*)d_in[8];
    const float* M1 = (const float*)d_in[9];
    const float* V1 = (const float*)d_in[10];
    const float* G2 = (const float*)d_in[11];
    const float* Be2= (const float*)d_in[12];
    const float* M2 = (const float*)d_in[13];
    const float* V2 = (const float*)d_in[14];
    const float* G3 = (const float*)d_in[15];
    const float* Be3= (const float*)d_in[16];
    const float* M3 = (const float*)d_in[17];
    const float* V3 = (const float*)d_in[18];

    float* ws  = (float*)d_ws;
    float* h1  = ws;                       // 25088*128
    float* h2  = h1 + (size_t)NPOS * J;    // 25088*128
    float* W1f = h2 + (size_t)NPOS * J;    // 32768
    float* b1f = W1f + C*J;                // 128
    float* W2f = b1f + J;                  // 4608
    float* b2f = W2f + P*9*D*D;            // 128
    float* W3f = b2f + J;                  // 32768
    float* b3f = W3f + P*D*C;              // 8192

    const int fold_tasks = C*J + J + P*9*D*D + J + P*D*C + P*C;  // 78592
    fold_params<<<(fold_tasks + 255)/256, 256, 0, stream>>>(
        W1, B1, W2, B2, W3, B3, G1, Be1, M1, V1, G2, Be2, M2, V2,
        G3, Be3, M3, V3, W1f, b1f, W2f, b2f, W3f, b3f);

    stage1<<<NPOS/64, 256, 0, stream>>>(x, W1f, b1f, h1);
    stage2<<<(NPOS*P)/256, 256, 0, stream>>>(h1, W2f, b2f, h2);
    stage3<<<NPOS/32, 256, 0, stream>>>(h2, W3f, b3f, x, (float*)d_out);
}

// Round 3
// 179.698 us; speedup vs baseline: 1.0974x; 1.0974x over previous
//
#include <hip/hip_runtime.h>

// Problem constants
#define BATCH 8
#define HH 56
#define WW 56
#define NPOS (BATCH*HH*WW)   // 25088
#define C 256
#define P 32
#define D 4
#define J (P*D)              // 128
#define EPS 1e-3f

typedef __attribute__((ext_vector_type(8))) short bf16x8_t;
typedef __attribute__((ext_vector_type(4))) float f32x4_t;

__device__ __forceinline__ unsigned short f2bf(float f) {
    union { float f; unsigned int i; } v; v.f = f;
    unsigned int r = v.i + 0x7fffu + ((v.i >> 16) & 1u);   // RNE
    return (unsigned short)(r >> 16);
}
__device__ __forceinline__ float bfhi2f(unsigned int u_shifted) {
    union { unsigned int i; float f; } v; v.i = u_shifted; return v.f;
}
// pack float4 -> 4 bf16 (truncation; error negligible for activations feeding GEMM)
__device__ __forceinline__ uint2 pack4_trunc(float4 v) {
    uint2 r;
    r.x = __builtin_amdgcn_perm(__float_as_uint(v.y), __float_as_uint(v.x), 0x07060302u);
    r.y = __builtin_amdgcn_perm(__float_as_uint(v.w), __float_as_uint(v.z), 0x07060302u);
    return r;
}

// ---------------------------------------------------------------------------
// Fold BN into conv weights/biases. Outputs:
//   W1bf: bf16 [j=128][c=256]  (B^T layout for stage1 MFMA)
//   b1f : fp32 [128]
//   W2f : fp32 (P,3,3,D,D) scaled ; b2f fp32 [128]
//   W3t : bf16 [p][c][d]  (b-frag layout for stage3) ; b3f fp32 [p][c]
// ---------------------------------------------------------------------------
__global__ __launch_bounds__(256) void fold_params(
    const float* __restrict__ W1, const float* __restrict__ B1,
    const float* __restrict__ W2, const float* __restrict__ B2,
    const float* __restrict__ W3, const float* __restrict__ B3,
    const float* __restrict__ G1, const float* __restrict__ Be1,
    const float* __restrict__ M1, const float* __restrict__ V1,
    const float* __restrict__ G2, const float* __restrict__ Be2,
    const float* __restrict__ M2, const float* __restrict__ V2,
    const float* __restrict__ G3, const float* __restrict__ Be3,
    const float* __restrict__ M3, const float* __restrict__ V3,
    unsigned short* __restrict__ W1bf, float* __restrict__ b1f,
    float* __restrict__ W2f, float* __restrict__ b2f,
    unsigned short* __restrict__ W3t, float* __restrict__ b3f)
{
    int idx = blockIdx.x * 256 + threadIdx.x;

    if (idx < C*J) {                       // W1bf[j][c]
        int j = idx >> 8, c = idx & 255;
        int p = j >> 2, d = j & 3;
        float s = G1[j] * rsqrtf(V1[j] + EPS);
        W1bf[idx] = f2bf(W1[(p*C + c)*D + d] * s);
        return;
    }
    idx -= C*J;
    if (idx < J) {
        float s = G1[idx] * rsqrtf(V1[idx] + EPS);
        b1f[idx] = B1[idx] * s + Be1[idx] - M1[idx] * s;
        return;
    }
    idx -= J;
    if (idx < P*9*D*D) {                   // W2f flat, scaled on dout
        int dd = idx & 3;
        int p = idx / (9*D*D);
        int j = p*4 + dd;
        float s = G2[j] * rsqrtf(V2[j] + EPS);
        W2f[idx] = W2[idx] * s;
        return;
    }
    idx -= P*9*D*D;
    if (idx < J) {
        float s = G2[idx] * rsqrtf(V2[idx] + EPS);
        b2f[idx] = B2[idx] * s + Be2[idx] - M2[idx] * s;
        return;
    }
    idx -= J;
    if (idx < P*D*C) {                     // W3t[p][c][d]
        int p = idx >> 10;
        int rem = idx & 1023;
        int c = rem >> 2, d = rem & 3;
        float s = G3[p*C + c] * rsqrtf(V3[p*C + c] + EPS);
        W3t[idx] = f2bf(W3[(p*D + d)*C + c] * s);
        return;
    }
    idx -= P*D*C;
    if (idx < P*C) {
        float s = G3[idx] * rsqrtf(V3[idx] + EPS);
        b3f[idx] = B3[idx] * s + Be3[idx] - M3[idx] * s;
        return;
    }
}

// ---------------------------------------------------------------------------
// Stage 1 (MFMA): h1[n][j] = relu( sum_c x[n][c]*W1f[c][j] + b1f[j] ), bf16 out.
// BM=32, N=128, BK=64. 256 threads = 4 waves; wave = 16M x 64N (4 n-frags).
// A: x fp32 -> bf16 staged in LDS; B: W1bf [j][c] staged in LDS.
// ---------------------------------------------------------------------------
__global__ __launch_bounds__(256) void stage1(
    const float* __restrict__ x, const unsigned short* __restrict__ W1bf,
    const float* __restrict__ b1f, unsigned short* __restrict__ h1)
{
    __shared__ unsigned short As[32][88];    // stride 176B: 16B-aligned, 2-way banks
    __shared__ unsigned short Bs[128][88];

    const int tid = threadIdx.x;
    const int n0blk = blockIdx.x * 32;
    const int wid = tid >> 6;
    const int l = tid & 63;
    const int l15 = l & 15;
    const int quad = l >> 4;
    const int m0w = (wid & 1) * 16;
    const int n0w = (wid >> 1) * 64;

    f32x4_t acc[4];
#pragma unroll
    for (int g = 0; g < 4; ++g) acc[g] = (f32x4_t){0.f, 0.f, 0.f, 0.f};

    for (int kc = 0; kc < C; kc += 64) {
        // stage A: 32 rows x 64 k fp32 -> bf16
        {
            int row = tid >> 3;
            int k8 = (tid & 7) * 8;
            const float* xp = &x[(size_t)(n0blk + row) * C + kc + k8];
            float4 v0 = *(const float4*)xp;
            float4 v1 = *(const float4*)(xp + 4);
            uint2 p0 = pack4_trunc(v0);
            uint2 p1 = pack4_trunc(v1);
            uint4 st; st.x = p0.x; st.y = p0.y; st.z = p1.x; st.w = p1.y;
            *(uint4*)&As[row][k8] = st;
        }
        // stage B: 128 rows x 64 k bf16
#pragma unroll
        for (int i = 0; i < 4; ++i) {
            int id = tid + i * 256;
            int row = id >> 3;
            int c8 = (id & 7) * 8;
            uint4 w = *(const uint4*)&W1bf[row * C + kc + c8];
            *(uint4*)&Bs[row][c8] = w;
        }
        __syncthreads();

#pragma unroll
        for (int k2 = 0; k2 < 64; k2 += 32) {
            bf16x8_t a = *(const bf16x8_t*)&As[m0w + l15][k2 + quad*8];
#pragma unroll
            for (int g = 0; g < 4; ++g) {
                bf16x8_t b = *(const bf16x8_t*)&Bs[n0w + g*16 + l15][k2 + quad*8];
                acc[g] = __builtin_amdgcn_mfma_f32_16x16x32_bf16(a, b, acc[g], 0, 0, 0);
            }
        }
        __syncthreads();
    }

#pragma unroll
    for (int g = 0; g < 4; ++g) {
        int j = n0w + g*16 + l15;
        float bias = b1f[j];
#pragma unroll
        for (int r = 0; r < 4; ++r) {
            int n = n0blk + m0w + quad*4 + r;
            float v = fmaxf(acc[g][r] + bias, 0.f);
            h1[(size_t)n * J + j] = f2bf(v);
        }
    }
}

// ---------------------------------------------------------------------------
// Stage 2: grouped 3x3 conv (32 groups of 4->4), SAME, +bias, ReLU. bf16 in/out.
// One thread per (n, p).
// ---------------------------------------------------------------------------
__global__ __launch_bounds__(256) void stage2(
    const unsigned short* __restrict__ h1,
    const float* __restrict__ W2f, const float* __restrict__ b2f,
    unsigned short* __restrict__ h2)
{
    __shared__ float w2s[P*9*D*D];   // 4608 floats
    __shared__ float b2s[J];

    const int tid = threadIdx.x;
    for (int i = tid; i < P*9*D*D; i += 256) w2s[i] = W2f[i];
    if (tid < J) b2s[tid] = b2f[tid];
    __syncthreads();

    const int t = blockIdx.x * 256 + tid;
    const int p = t & 31;
    const int n = t >> 5;
    const int w = n % WW;
    const int h = (n / WW) % HH;
    const int b = n / (HH*WW);

    float a0 = b2s[p*4+0], a1 = b2s[p*4+1], a2 = b2s[p*4+2], a3 = b2s[p*4+3];

#pragma unroll
    for (int ky = 0; ky < 3; ++ky) {
        int yy = h + ky - 1;
        if (yy < 0 || yy >= HH) continue;
#pragma unroll
        for (int kx = 0; kx < 3; ++kx) {
            int xx = w + kx - 1;
            if (xx < 0 || xx >= WW) continue;
            uint2 hv = *(const uint2*)&h1[(size_t)((b*HH + yy)*WW + xx) * J + p*4];
            float f0 = bfhi2f(hv.x << 16);
            float f1 = bfhi2f(hv.x & 0xffff0000u);
            float f2 = bfhi2f(hv.y << 16);
            float f3 = bfhi2f(hv.y & 0xffff0000u);
            const float* wp = &w2s[(p*9 + ky*3 + kx) * 16];
            a0 = fmaf(f0, wp[0],  a0); a1 = fmaf(f0, wp[1],  a1);
            a2 = fmaf(f0, wp[2],  a2); a3 = fmaf(f0, wp[3],  a3);
            a0 = fmaf(f1, wp[4],  a0); a1 = fmaf(f1, wp[5],  a1);
            a2 = fmaf(f1, wp[6],  a2); a3 = fmaf(f1, wp[7],  a3);
            a0 = fmaf(f2, wp[8],  a0); a1 = fmaf(f2, wp[9],  a1);
            a2 = fmaf(f2, wp[10], a2); a3 = fmaf(f2, wp[11], a3);
            a0 = fmaf(f3, wp[12], a0); a1 = fmaf(f3, wp[13], a1);
            a2 = fmaf(f3, wp[14], a2); a3 = fmaf(f3, wp[15], a3);
        }
    }
    uint2 o;
    o.x = (unsigned int)f2bf(fmaxf(a0, 0.f)) | ((unsigned int)f2bf(fmaxf(a1, 0.f)) << 16);
    o.y = (unsigned int)f2bf(fmaxf(a2, 0.f)) | ((unsigned int)f2bf(fmaxf(a3, 0.f)) << 16);
    *(uint2*)&h2[(size_t)n * J + p*4] = o;
}

// ---------------------------------------------------------------------------
// Stage 3 (MFMA): out[n][c] = relu( x[n][c] + sum_p relu( h2_p . W3_p + b3_p ) )
// Block: n-tile 16, 4 waves; wave w -> c-range [w*64, w*64+64) = 4 c-tiles.
// Per p: one MFMA (K=4 of 32 used; b-frag zeroed for k>=4), bias via C operand,
// per-path relu+accumulate in C-layout registers.
// ---------------------------------------------------------------------------
__global__ __launch_bounds__(256) void stage3(
    const unsigned short* __restrict__ h2,
    const unsigned short* __restrict__ W3t, const float* __restrict__ b3f,
    const float* __restrict__ x, float* __restrict__ out)
{
    __shared__ unsigned short h2s[16][136];   // stride 272B: b64-aligned, 2-way banks

    const int tid = threadIdx.x;
    const int n0 = blockIdx.x * 16;
    {
        int row = tid >> 4;
        int col = (tid & 15) * 8;
        *(uint4*)&h2s[row][col] = *(const uint4*)&h2[(size_t)(n0 + row) * J + col];
    }
    __syncthreads();

    const int l = tid & 63;
    const int l15 = l & 15;
    const int quad = l >> 4;
    const int c0w = (tid >> 6) * 64;

    float acc[4][4];
#pragma unroll
    for (int ct = 0; ct < 4; ++ct)
#pragma unroll
        for (int r = 0; r < 4; ++r) acc[ct][r] = 0.f;

    for (int p = 0; p < P; ++p) {
        union { bf16x8_t v; uint2 u2[2]; } af;
        af.u2[0] = *(const uint2*)&h2s[l15][p*4];   // A[m=l15][k=0..3], k>=4 killed by b=0
        af.u2[1] = make_uint2(0u, 0u);
#pragma unroll
        for (int ct = 0; ct < 4; ++ct) {
            int c = c0w + ct*16 + l15;
            uint2 wv = make_uint2(0u, 0u);
            if (quad == 0) wv = *(const uint2*)&W3t[((size_t)p * C + c) * D];
            union { bf16x8_t v; uint2 u2[2]; } bfr;
            bfr.u2[0] = wv;
            bfr.u2[1] = make_uint2(0u, 0u);
            float bias = b3f[p * C + c];
            f32x4_t cin = {bias, bias, bias, bias};
            f32x4_t z = __builtin_amdgcn_mfma_f32_16x16x32_bf16(af.v, bfr.v, cin, 0, 0, 0);
#pragma unroll
            for (int r = 0; r < 4; ++r) acc[ct][r] += fmaxf(z[r], 0.f);
        }
    }

#pragma unroll
    for (int ct = 0; ct < 4; ++ct) {
        int c = c0w + ct*16 + l15;
#pragma unroll
        for (int r = 0; r < 4; ++r) {
            int n = n0 + quad*4 + r;
            float v = acc[ct][r] + x[(size_t)n * C + c];
            out[(size_t)n * C + c] = fmaxf(v, 0.f);
        }
    }
}

// ---------------------------------------------------------------------------
extern "C" void kernel_launch(void* const* d_in, const int* in_sizes, int n_in,
                              void* d_out, int out_size, void* d_ws, size_t ws_size,
                              hipStream_t stream) {
    const float* x  = (const float*)d_in[0];
    const float* W1 = (const float*)d_in[1];
    const float* B1 = (const float*)d_in[2];
    const float* W2 = (const float*)d_in[3];
    const float* B2 = (const float*)d_in[4];
    const float* W3 = (const float*)d_in[5];
    const float* B3 = (const float*)d_in[6];
    const float* G1 = (const float*)d_in[7];
    const float* Be1= (const float*)d_in[8];
    const float* M1 = (const float*)d_in[9];
    const float* V1 = (const float*)d_in[10];
    const float* G2 = (const float*)d_in[11];
    const float* Be2= (const float*)d_in[12];
    const float* M2 = (const float*)d_in[13];
    const float* V2 = (const float*)d_in[14];
    const float* G3 = (const float*)d_in[15];
    const float* Be3= (const float*)d_in[16];
    const float* M3 = (const float*)d_in[17];
    const float* V3 = (const float*)d_in[18];

    char* wsb = (char*)d_ws;
    unsigned short* h1   = (unsigned short*)(wsb + 0);          // 6,422,528 B
    unsigned short* h2   = (unsigned short*)(wsb + 6422528);    // 6,422,528 B
    unsigned short* W1bf = (unsigned short*)(wsb + 12845056);   // 65,536 B
    unsigned short* W3t  = (unsigned short*)(wsb + 12910592);   // 65,536 B
    float*          W2f  = (float*)(wsb + 12976128);            // 18,432 B
    float*          b1f  = (float*)(wsb + 12994560);            // 512 B
    float*          b2f  = (float*)(wsb + 12995072);            // 512 B
    float*          b3f  = (float*)(wsb + 12995584);            // 32,768 B

    const int fold_tasks = C*J + J + P*9*D*D + J + P*D*C + P*C;  // 78592
    fold_params<<<(fold_tasks + 255)/256, 256, 0, stream>>>(
        W1, B1, W2, B2, W3, B3, G1, Be1, M1, V1, G2, Be2, M2, V2,
        G3, Be3, M3, V3, W1bf, b1f, W2f, b2f, W3t, b3f);

    stage1<<<NPOS/32, 256, 0, stream>>>(x, W1bf, b1f, h1);
    stage2<<<(NPOS*P)/256, 256, 0, stream>>>(h1, W2f, b2f, h2);
    stage3<<<NPOS/16, 256, 0, stream>>>(h2, W3t, b3f, x, (float*)d_out);
}